// Round 4
// baseline (547224.121 us; speedup 1.0000x reference)
//
#include <hip/hip_runtime.h>
#include <math.h>

// ControlledNODE: sequential RK4 scan, T=65536, 1 block / 128 threads (2 waves).
// R3: execution restructured for latency, arithmetic kept BIT-IDENTICAL to the
// R0 kernel that passed at absmax 6.1e-5. Lesson from R1/R2: any re-association
// of the layer sums re-rolls the 65536-step trajectory and blew the threshold
// (identical 1.22e-3 error with two different transcendental variants proved the
// error was structural association, not rcp/tanh approximations).
//
//  - L1/L2: thread j owns column j, R0's exact fma chains
//    (a0 = bias + k=0,4,8,... ; a1 = k=1,5,...; final (a0+a1)+(a2+a3);
//     L1 u-terms appended sequentially to a0)
//  - L3 + RK combine: replicated on ALL threads with R0's exact partial
//    structure ((p0+p1)+(p2+p3))+b3  ->  no pbuf barrier, no x-broadcast barrier
//  - activation exchange: own-wave half via v_readlane (bit-exact value move),
//    cross-wave half via wave-uniform ds_read_b128 broadcast
//  - 2 barriers/stage = 8/step (R0: 16)

constexpr int T_STEPS = 65536;

__device__ __forceinline__ float rl_f(float v, int i) {
    return __uint_as_float(__builtin_amdgcn_readlane(__float_as_uint(v), i));
}
__device__ __forceinline__ float silu_f(float a) {
    // EXACT R0 form: a / (1 + exp2-based expf), IEEE divide
    return a / (1.0f + __expf(-a));
}

__global__ __launch_bounds__(128, 1)
void node_scan(const float* __restrict__ U,
               const float* __restrict__ h0,
               const float* __restrict__ W1, const float* __restrict__ b1,
               const float* __restrict__ W2, const float* __restrict__ b2,
               const float* __restrict__ W3, const float* __restrict__ b3,
               const float* __restrict__ Wd, const float* __restrict__ bd,
               const float* __restrict__ Wt, const float* __restrict__ bt,
               const float* __restrict__ Wc, const float* __restrict__ bc,
               float* __restrict__ out)
{
    const int tid = threadIdx.x;
    const int l   = tid & 63;   // lane
    const int wv  = tid >> 6;   // wave 0/1
    const int m   = tid & 31;   // owned state index (replicated 4x across block)

    __shared__ __align__(16) float z1buf[128];
    __shared__ __align__(16) float z2buf[128];

    // ---- weights into registers (thread j = column j) ----
    float w1r[40];
#pragma unroll
    for (int i = 0; i < 40; ++i) w1r[i] = W1[i * 128 + tid];
    const float b1r = b1[tid];

    float w2r[128];
#pragma unroll
    for (int i = 0; i < 128; ++i) w2r[i] = W2[i * 128 + tid];
    const float b2r = b2[tid];

    // full W3 column for output m (replicated combine)
    float w3f[128];
#pragma unroll
    for (int i = 0; i < 128; ++i) w3f[i] = W3[i * 32 + m];
    const float b3r = b3[m];

    // heads: wave0 -> d, wave1 -> t,c (same 32-lane xor trees as R0)
    const float wdr = (l < 32) ? Wd[l] : 0.0f;
    const float wtr = (l < 32) ? Wt[l] : 0.0f;
    const float wcr = (l < 32) ? Wc[l] : 0.0f;
    const float bd0 = bd[0], bt0 = bt[0], bc0 = bc[0];

    const float DT  = 5.0f / 60.0f;
    const float HDT = 0.5f * DT;
    const float W6  = DT / 6.0f;

    // state replicated: lane holds h[m], x[m]; identical bits on all lanes
    float h = h0[m];
    float x = h;
    float kacc = 0.0f;

    float4 ua = *(const float4*)(U);
    float4 ub = *(const float4*)(U + 4);

    for (int t = 0; t < T_STEPS; ++t) {
        const int tn = (t + 1 < T_STEPS) ? (t + 1) : t;
        const float4 na = *(const float4*)(U + tn * 8);
        const float4 nb = *(const float4*)(U + tn * 8 + 4);

        // ---- heads from current h (pre-update); R0's exact trees ----
        if (wv == 0) {
            float pd = h * wdr;                       // lanes>=32 contribute 0
#pragma unroll
            for (int s = 16; s >= 1; s >>= 1) pd += __shfl_xor(pd, s);
            if (l == 0) out[t] = pd + bd0;
        } else {
            float pt = h * wtr;
            float pc = h * wcr;
#pragma unroll
            for (int s = 16; s >= 1; s >>= 1) {
                pt += __shfl_xor(pt, s);
                pc += __shfl_xor(pc, s);
            }
            if (l == 0) {
                out[T_STEPS + t]     = pt + bt0;
                out[2 * T_STEPS + t] = pc + bc0;
            }
        }

        const float us[8] = {ua.x, ua.y, ua.z, ua.w, ub.x, ub.y, ub.z, ub.w};

#pragma unroll
        for (int st = 0; st < 4; ++st) {
            // ---- L1: z1[j] = silu([x,u] @ W1 + b1), R0's exact chains ----
            float a0 = b1r, a1 = 0.0f, a2 = 0.0f, a3 = 0.0f;
#pragma unroll
            for (int i4 = 0; i4 < 8; ++i4) {
                a0 += rl_f(x, 4 * i4)     * w1r[4 * i4];
                a1 += rl_f(x, 4 * i4 + 1) * w1r[4 * i4 + 1];
                a2 += rl_f(x, 4 * i4 + 2) * w1r[4 * i4 + 2];
                a3 += rl_f(x, 4 * i4 + 3) * w1r[4 * i4 + 3];
            }
#pragma unroll
            for (int i = 0; i < 8; ++i) a0 += us[i] * w1r[32 + i];
            const float z1 = silu_f((a0 + a1) + (a2 + a3));
            z1buf[tid] = z1;
            __syncthreads();

            // ---- L2: z2[j], k = 0..127 in R0 order; own half via readlane ----
            a0 = b2r; a1 = 0.0f; a2 = 0.0f; a3 = 0.0f;
            if (wv == 0) {
#pragma unroll
                for (int i4 = 0; i4 < 16; ++i4) {
                    a0 += rl_f(z1, 4 * i4)     * w2r[4 * i4];
                    a1 += rl_f(z1, 4 * i4 + 1) * w2r[4 * i4 + 1];
                    a2 += rl_f(z1, 4 * i4 + 2) * w2r[4 * i4 + 2];
                    a3 += rl_f(z1, 4 * i4 + 3) * w2r[4 * i4 + 3];
                }
#pragma unroll
                for (int i4 = 16; i4 < 32; ++i4) {
                    const float4 v = *(const float4*)(z1buf + 4 * i4);
                    a0 += v.x * w2r[4 * i4];
                    a1 += v.y * w2r[4 * i4 + 1];
                    a2 += v.z * w2r[4 * i4 + 2];
                    a3 += v.w * w2r[4 * i4 + 3];
                }
            } else {
#pragma unroll
                for (int i4 = 0; i4 < 16; ++i4) {
                    const float4 v = *(const float4*)(z1buf + 4 * i4);
                    a0 += v.x * w2r[4 * i4];
                    a1 += v.y * w2r[4 * i4 + 1];
                    a2 += v.z * w2r[4 * i4 + 2];
                    a3 += v.w * w2r[4 * i4 + 3];
                }
#pragma unroll
                for (int i4 = 16; i4 < 32; ++i4) {
                    a0 += rl_f(z1, 4 * i4 - 64)     * w2r[4 * i4];
                    a1 += rl_f(z1, 4 * i4 - 64 + 1) * w2r[4 * i4 + 1];
                    a2 += rl_f(z1, 4 * i4 - 64 + 2) * w2r[4 * i4 + 2];
                    a3 += rl_f(z1, 4 * i4 - 64 + 3) * w2r[4 * i4 + 3];
                }
            }
            const float z2 = silu_f((a0 + a1) + (a2 + a3));
            z2buf[tid] = z2;
            __syncthreads();

            // ---- L3 replicated: R0's 4 segment partials, exact structure ----
            float pg[4];
#pragma unroll
            for (int g = 0; g < 4; ++g) {
                float c0 = 0.0f, c1 = 0.0f, c2 = 0.0f, c3 = 0.0f;
                if ((g >> 1) == wv) {  // segment lives in this wave's lanes
#pragma unroll
                    for (int i4 = 0; i4 < 8; ++i4) {
                        const int k = 32 * g + 4 * i4;
                        c0 += rl_f(z2, (k)     & 63) * w3f[k];
                        c1 += rl_f(z2, (k + 1) & 63) * w3f[k + 1];
                        c2 += rl_f(z2, (k + 2) & 63) * w3f[k + 2];
                        c3 += rl_f(z2, (k + 3) & 63) * w3f[k + 3];
                    }
                } else {
#pragma unroll
                    for (int i4 = 0; i4 < 8; ++i4) {
                        const int k = 32 * g + 4 * i4;
                        const float4 v = *(const float4*)(z2buf + k);
                        c0 += v.x * w3f[k];
                        c1 += v.y * w3f[k + 1];
                        c2 += v.z * w3f[k + 2];
                        c3 += v.w * w3f[k + 3];
                    }
                }
                pg[g] = (c0 + c1) + (c2 + c3);
            }
            const float drift = ((pg[0] + pg[1]) + (pg[2] + pg[3])) + b3r;

            // ---- RK combine, replicated; EXACT R0 expressions ----
            {
                const float s = x;
                const float k = 0.02f * drift - 0.1f * s;
                if (st == 0) {
                    kacc = k;
                    x = h + HDT * k;
                } else if (st == 1) {
                    kacc += 2.0f * k;
                    x = h + HDT * k;
                } else if (st == 2) {
                    kacc += 2.0f * k;
                    x = h + DT * k;
                } else {
                    kacc += k;
                    float hn = h + W6 * kacc;
                    if (!isfinite(hn)) hn = 0.0f;   // nan_to_num BEFORE tanh
                    hn = tanhf(hn);
                    hn = fminf(fmaxf(hn, -5.0f), 5.0f);
                    h = hn;
                    x = hn;
                }
            }
        }

        ua = na; ub = nb;
    }

    if (tid < 32) out[3 * T_STEPS + tid] = h;
}

extern "C" void kernel_launch(void* const* d_in, const int* in_sizes, int n_in,
                              void* d_out, int out_size, void* d_ws, size_t ws_size,
                              hipStream_t stream) {
    const float* U  = (const float*)d_in[0];
    const float* h0 = (const float*)d_in[1];
    const float* W1 = (const float*)d_in[2];
    const float* b1 = (const float*)d_in[3];
    const float* W2 = (const float*)d_in[4];
    const float* b2 = (const float*)d_in[5];
    const float* W3 = (const float*)d_in[6];
    const float* b3 = (const float*)d_in[7];
    const float* Wd = (const float*)d_in[8];
    const float* bd = (const float*)d_in[9];
    const float* Wt = (const float*)d_in[10];
    const float* bt = (const float*)d_in[11];
    const float* Wc = (const float*)d_in[12];
    const float* bc = (const float*)d_in[13];
    float* out = (float*)d_out;

    node_scan<<<1, 128, 0, stream>>>(U, h0, W1, b1, W2, b2, W3, b3,
                                     Wd, bd, Wt, bt, Wc, bc, out);
}